// Round 4
// baseline (203.466 us; speedup 1.0000x reference)
//
#include <hip/hip_runtime.h>
#include <hip/hip_bf16.h>

// PAM module R4: q/k/v 1x1 projections -> bf16 MFMA attention -> gamma*out + x.
// Key change vs R3: LDS reuse factor in attn was exactly 1.0 (each wave consumed
// only its own m-quarter / V-chunks), so the main loop now reads MFMA fragments
// DIRECTLY global->VGPR from fragment-major workspace layouts written by proj:
//   zero LDS, zero barriers in the 32-iteration main loop; waves free-run.
// P stays in registers via ds_bpermute C->B-frag transform (R3-proven).
// LDS only for the end O-reduction across the 4 m-quarter waves + epilogue.
//
// Workspace layouts (bf16, chunk = 64 lanes x 16B = 1KB, frag-major):
//   qf_ws[b][strip64][ni][kc][lane]           8MB
//   kt   [b][tile128][mb][kc][lane]           8MB  (mb = m-block 0..7)
//   vt   [b][tile128][cb*16+wq][l16]{8}       8MB  (wq = w*4+quad)

typedef __bf16 v8bf __attribute__((ext_vector_type(8)));
typedef float  v4f  __attribute__((ext_vector_type(4)));

#define B_ 8
#define C_ 128
#define N_ 4096

static __device__ __forceinline__ unsigned short f2bf_rne(float f) {
    union { float f; unsigned u; } v; v.f = f;
    return (unsigned short)((v.u + 0x7fffu + ((v.u >> 16) & 1u)) >> 16);
}
static __device__ __forceinline__ unsigned fbits(float f) {
    union { float f; unsigned u; } v; v.f = f; return v.u;
}

// ---------------------------------------------------------------------------
// Kernel 1: one block per (projection pp, tile t, batch b). 256 thr / 4 waves.
// W = pw*diag(dw) folded to bf16. GEMM 128x128x128 via 16x16x32 MFMA.
// Result bounced through LDS scratch (stride 136) then copied out coalesced in
// fragment-major order.
// ---------------------------------------------------------------------------
__global__ __launch_bounds__(256, 2) void proj_kernel(
    const float* __restrict__ x,
    const float* __restrict__ dw_q, const float* __restrict__ pw_q,
    const float* __restrict__ dw_k, const float* __restrict__ pw_k,
    const float* __restrict__ dw_v, const float* __restrict__ pw_v,
    unsigned short* __restrict__ qf_ws, unsigned short* __restrict__ kt,
    unsigned short* __restrict__ vt)
{
    __shared__ unsigned short xT[128 * 136];  // xT[n][c]
    __shared__ unsigned short Ws[128 * 136];  // W[o][c]; reused as store scratch

    const int bid = blockIdx.x;
    const int bb  = bid & 7;
    const int t   = (bid >> 3) & 31;
    const int pp  = bid >> 8;            // 0:q 1:k 2:v
    const int n0  = t * 128;
    const int tid = threadIdx.x;
    const int w    = tid >> 6;
    const int lane = tid & 63;
    const int quad = lane >> 4;
    const int l16  = lane & 15;

    // ---- stage xT[n][c] (transpose + cvt bf16); float4 reads along n
    #pragma unroll
    for (int k = 0; k < 16; ++k) {
        const int idx = tid + k * 256;          // 4096 float4
        const int c  = idx >> 5;
        const int nq = idx & 31;
        float4 f = *(const float4*)(x + ((size_t)(bb * C_ + c)) * N_ + n0 + nq * 4);
        xT[(nq * 4 + 0) * 136 + c] = f2bf_rne(f.x);
        xT[(nq * 4 + 1) * 136 + c] = f2bf_rne(f.y);
        xT[(nq * 4 + 2) * 136 + c] = f2bf_rne(f.z);
        xT[(nq * 4 + 3) * 136 + c] = f2bf_rne(f.w);
    }
    // ---- stage Ws[o][c] = pw[o][c]*dw[c], bf16
    const float* pw = (pp == 0) ? pw_q : (pp == 1) ? pw_k : pw_v;
    const float* dw = (pp == 0) ? dw_q : (pp == 1) ? dw_k : dw_v;
    #pragma unroll
    for (int k = 0; k < 16; ++k) {
        const int idx = tid + k * 256;
        const int o  = idx >> 5;
        const int c4 = (idx & 31) * 4;
        float4 p4 = *(const float4*)(pw + o * 128 + c4);
        float4 d4 = *(const float4*)(dw + c4);
        unsigned lo = (unsigned)f2bf_rne(p4.x * d4.x) | ((unsigned)f2bf_rne(p4.y * d4.y) << 16);
        unsigned hi = (unsigned)f2bf_rne(p4.z * d4.z) | ((unsigned)f2bf_rne(p4.w * d4.w) << 16);
        *(unsigned long long*)&Ws[o * 136 + c4] =
            (unsigned long long)lo | ((unsigned long long)hi << 32);
    }
    __syncthreads();

    // q/k: D[n|m][o] = xT(A rows) * Ws(B cols);  v: D[o][m] = Ws(A rows) * xT(B cols)
    const unsigned short* As = (pp < 2) ? xT : Ws;
    const unsigned short* Bs = (pp < 2) ? Ws : xT;

    v4f acc[2][8];   // [mi][cb]: rows = w*32 + mi*16, cols = cb*16
    #pragma unroll
    for (int i = 0; i < 2; ++i)
        #pragma unroll
        for (int j = 0; j < 8; ++j)
            acc[i][j] = (v4f){0.f, 0.f, 0.f, 0.f};

    #pragma unroll
    for (int kc = 0; kc < 4; ++kc) {
        v8bf av[2];
        #pragma unroll
        for (int i = 0; i < 2; ++i)
            av[i] = *(const v8bf*)&As[(w * 32 + i * 16 + l16) * 136 + kc * 32 + quad * 8];
        #pragma unroll
        for (int cb = 0; cb < 8; ++cb) {
            v8bf bv = *(const v8bf*)&Bs[(cb * 16 + l16) * 136 + kc * 32 + quad * 8];
            acc[0][cb] = __builtin_amdgcn_mfma_f32_16x16x32_bf16(av[0], bv, acc[0][cb], 0, 0, 0);
            acc[1][cb] = __builtin_amdgcn_mfma_f32_16x16x32_bf16(av[1], bv, acc[1][cb], 0, 0, 0);
        }
    }
    __syncthreads();   // done reading xT/Ws; Ws becomes scratch

    // ---- D-layout -> plain scratch [row][136]
    unsigned short* sc = Ws;
    #pragma unroll
    for (int mi = 0; mi < 2; ++mi)
        #pragma unroll
        for (int cb = 0; cb < 8; ++cb)
            #pragma unroll
            for (int r = 0; r < 4; ++r)
                sc[(w * 32 + mi * 16 + quad * 4 + r) * 136 + cb * 16 + l16] =
                    f2bf_rne(acc[mi][cb][r]);
    __syncthreads();

    // ---- coalesced fragment-major global copy (8 passes x 4KB)
    if (pp == 0) {
        // chunks g = strip*16 + ni*4 + kc; element: n = strip*64+ni*16+l16, c = kc*32+quad*8
        unsigned short* dst = qf_ws + ((size_t)(bb * 64 + t * 2)) * 8192;
        #pragma unroll
        for (int p = 0; p < 8; ++p) {
            const int g     = p * 4 + w;
            const int strip = g >> 4, ni = (g >> 2) & 3, kc = g & 3;
            *(uint4*)(dst + ((size_t)g * 64 + lane) * 8) =
                *(const uint4*)&sc[(strip * 64 + ni * 16 + l16) * 136 + kc * 32 + quad * 8];
        }
    } else if (pp == 1) {
        // chunks g = mb*4 + kc; element: m = mb*16+l16, c = kc*32+quad*8
        unsigned short* dst = kt + ((size_t)(bb * 32 + t)) * 16384;
        #pragma unroll
        for (int p = 0; p < 8; ++p) {
            const int g  = p * 4 + w;
            const int mb = g >> 2, kc = g & 3;
            *(uint4*)(dst + ((size_t)g * 64 + lane) * 8) =
                *(const uint4*)&sc[(mb * 16 + l16) * 136 + kc * 32 + quad * 8];
        }
    } else {
        // 16B units d: cb = d>>8, wq = (d>>4)&15, l = d&15; element c = cb*16+l, m = wq*8..
        unsigned short* dst = vt + ((size_t)(bb * 32 + t)) * 16384;
        #pragma unroll
        for (int p = 0; p < 8; ++p) {
            const int d  = p * 256 + tid;
            const int cb = d >> 8, wq = (d >> 4) & 15, l = d & 15;
            *(uint4*)(dst + (size_t)d * 8) =
                *(const uint4*)&sc[(cb * 16 + l) * 136 + wq * 8];
        }
    }
}

// ---------------------------------------------------------------------------
// Kernel 2: attention. grid 512 = (b = bid&7, 64-row n-strip = bid>>3).
// 256 thr / 4 waves; wave = m-quarter, full c=128, full n=64. Main loop:
// direct global->VGPR fragment loads (1KB coalesced), S^T = K^T Q, exp,
// bpermute C->B-frag, O += V*P. NO LDS / NO barriers until the end reduction.
// ---------------------------------------------------------------------------
__global__ __launch_bounds__(256, 2) void attn_kernel(
    const unsigned short* __restrict__ qf_ws, const unsigned short* __restrict__ kt,
    const unsigned short* __restrict__ vt, const float* __restrict__ x,
    const float* __restrict__ gamma, float* __restrict__ out)
{
    __shared__ float red[64 * 132];   // O reduction scratch [n][c] (+pad)
    __shared__ float l_s[4][64];

    const int bid = blockIdx.x;
    const int bb  = bid & 7;
    const int s   = bid >> 3;        // n-strip 0..63
    const int n0  = s * 64;
    const int tid = threadIdx.x;
    const int w    = tid >> 6;       // wave = m-quarter owner
    const int lane = tid & 63;
    const int quad = lane >> 4;
    const int l16  = lane & 15;

    // ---- Q fragments, iteration-invariant (B-operand of S^T)
    v8bf qf[4][4];
    {
        const unsigned short* qb = qf_ws + ((size_t)(bb * 64 + s)) * 8192;
        #pragma unroll
        for (int ni = 0; ni < 4; ++ni)
            #pragma unroll
            for (int kc = 0; kc < 4; ++kc)
                qf[ni][kc] = *(const v8bf*)(qb + ((size_t)(ni * 4 + kc) * 64 + lane) * 8);
    }

    v4f oacc[8][4];  // [cb][ni] partial O over this wave's 32-m subset
    #pragma unroll
    for (int i = 0; i < 8; ++i)
        #pragma unroll
        for (int j = 0; j < 4; ++j)
            oacc[i][j] = (v4f){0.f, 0.f, 0.f, 0.f};
    float lpart[4] = {0.f, 0.f, 0.f, 0.f};

    const int la = ((((quad & 1) << 1) << 4) + l16) << 2;  // bpermute byte idx
    const int lb = la + 64;

    const unsigned short* kbase = kt + ((size_t)(bb * 32)) * 16384 + ((size_t)(w * 8) * 64 + lane) * 8;
    const unsigned short* vbase = vt + ((size_t)(bb * 32)) * 16384 + ((size_t)(w * 64 + lane)) * 8;

    for (int it = 0; it < 32; ++it) {
        const unsigned short* kp = kbase + (size_t)it * 16384;
        const unsigned short* vp = vbase + (size_t)it * 16384;

        // ---- K fragments (2 mb x 4 kc, each a coalesced 1KB wave load)
        v8bf kfr[2][4];
        #pragma unroll
        for (int mi = 0; mi < 2; ++mi)
            #pragma unroll
            for (int kc = 0; kc < 4; ++kc)
                kfr[mi][kc] = *(const v8bf*)(kp + (size_t)((mi * 4 + kc) * 64) * 8);

        // ---- S^T (m-quarter x n64)
        v4f sacc[2][4];
        #pragma unroll
        for (int mi = 0; mi < 2; ++mi)
            #pragma unroll
            for (int ni = 0; ni < 4; ++ni) sacc[mi][ni] = (v4f){0.f, 0.f, 0.f, 0.f};
        #pragma unroll
        for (int mi = 0; mi < 2; ++mi)
            #pragma unroll
            for (int kc = 0; kc < 4; ++kc)
                #pragma unroll
                for (int ni = 0; ni < 4; ++ni)
                    sacc[mi][ni] = __builtin_amdgcn_mfma_f32_16x16x32_bf16(
                        kfr[mi][kc], qf[ni][kc], sacc[mi][ni], 0, 0, 0);

        // ---- exp + pack
        unsigned pk_[2][4][2];
        #pragma unroll
        for (int mi = 0; mi < 2; ++mi)
            #pragma unroll
            for (int ni = 0; ni < 4; ++ni) {
                float e0 = __expf(sacc[mi][ni][0]), e1 = __expf(sacc[mi][ni][1]);
                float e2 = __expf(sacc[mi][ni][2]), e3 = __expf(sacc[mi][ni][3]);
                lpart[ni] += (e0 + e1) + (e2 + e3);
                pk_[mi][ni][0] = (fbits(e0) >> 16) | (fbits(e1) & 0xffff0000u);
                pk_[mi][ni][1] = (fbits(e2) >> 16) | (fbits(e3) & 0xffff0000u);
            }

        // ---- C-layout -> B-frag via bpermute (R3-proven mapping)
        v8bf pf[4];
        #pragma unroll
        for (int ni = 0; ni < 4; ++ni) {
            unsigned sLo = (quad < 2) ? pk_[0][ni][0] : pk_[1][ni][0];
            unsigned sHi = (quad < 2) ? pk_[0][ni][1] : pk_[1][ni][1];
            union { unsigned u[4]; v8bf v; } pu;
            pu.u[0] = (unsigned)__builtin_amdgcn_ds_bpermute(la, (int)sLo);
            pu.u[1] = (unsigned)__builtin_amdgcn_ds_bpermute(la, (int)sHi);
            pu.u[2] = (unsigned)__builtin_amdgcn_ds_bpermute(lb, (int)sLo);
            pu.u[3] = (unsigned)__builtin_amdgcn_ds_bpermute(lb, (int)sHi);
            pf[ni] = pu.v;
        }

        // ---- O[c][n] += V * P  (V frags: 8 coalesced 1KB wave loads)
        #pragma unroll
        for (int cb = 0; cb < 8; ++cb) {
            v8bf vv = *(const v8bf*)(vp + (size_t)(cb * 256) * 8);
            #pragma unroll
            for (int ni = 0; ni < 4; ++ni)
                oacc[cb][ni] = __builtin_amdgcn_mfma_f32_16x16x32_bf16(
                    vv, pf[ni], oacc[cb][ni], 0, 0, 0);
        }
    }

    // ---- softmax denominators (per-wave partials over its 32-m subset)
    #pragma unroll
    for (int ni = 0; ni < 4; ++ni) {
        float r = lpart[ni];
        r += __shfl_xor(r, 16);
        r += __shfl_xor(r, 32);
        if (lane < 16) l_s[w][ni * 16 + lane] = r;
    }

    // ---- O reduction across the 4 m-quarter waves
    for (int rw = 0; rw < 4; ++rw) {
        if (w == rw) {
            #pragma unroll
            for (int cb = 0; cb < 8; ++cb)
                #pragma unroll
                for (int ni = 0; ni < 4; ++ni) {
                    float* p = &red[(ni * 16 + l16) * 132 + cb * 16 + quad * 4];
                    if (rw == 0) *(v4f*)p = oacc[cb][ni];
                    else {
                        v4f tv = *(const v4f*)p;
                        tv += oacc[cb][ni];
                        *(v4f*)p = tv;
                    }
                }
        }
        __syncthreads();
    }

    // ---- epilogue: out = gamma * O / l + x   (lane = n, coalesced)
    const float g = gamma[0];
    const float li = 1.0f / (((l_s[0][lane] + l_s[1][lane]) + (l_s[2][lane] + l_s[3][lane])));
    #pragma unroll
    for (int ci = 0; ci < 32; ++ci) {
        const int c = w * 32 + ci;
        const size_t idx = ((size_t)(bb * C_ + c)) * N_ + n0 + lane;
        out[idx] = g * red[lane * 132 + c] * li + x[idx];
    }
}

// ---------------------------------------------------------------------------
extern "C" void kernel_launch(void* const* d_in, const int* in_sizes, int n_in,
                              void* d_out, int out_size, void* d_ws, size_t ws_size,
                              hipStream_t stream)
{
    (void)in_sizes; (void)n_in; (void)out_size; (void)ws_size;
    const float* x     = (const float*)d_in[0];
    const float* dw_q  = (const float*)d_in[1];
    const float* pw_q  = (const float*)d_in[2];
    const float* dw_k  = (const float*)d_in[3];
    const float* pw_k  = (const float*)d_in[4];
    const float* dw_v  = (const float*)d_in[5];
    const float* pw_v  = (const float*)d_in[6];
    const float* gamma = (const float*)d_in[7];
    float* out = (float*)d_out;

    unsigned short* qf_ws = (unsigned short*)d_ws;                  // 8 MB
    unsigned short* kt    = qf_ws + (size_t)B_ * N_ * C_;           // 8 MB
    unsigned short* vt    = kt    + (size_t)B_ * N_ * C_;           // 8 MB

    proj_kernel<<<dim3(768), dim3(256), 0, stream>>>(
        x, dw_q, pw_q, dw_k, pw_k, dw_v, pw_v, qf_ws, kt, vt);
    attn_kernel<<<dim3(512), dim3(256), 0, stream>>>(
        qf_ws, kt, vt, x, gamma, out);
}